// Round 12
// baseline (51.094 us; speedup 1.0000x reference)
//
#include <hip/hip_runtime.h>

#define MT 64     // number of event types M
#define KK 4      // number of kernels K
#define NBK 4096  // scan blocks (512 WGs x 8 waves)
#define MAXB 49   // events/block per LDS chunk (N <= 200704 in one chunk; larger N loops)

// ---------- helpers ----------
__device__ __forceinline__ float wredf(float v) {
  #pragma unroll
  for (int off = 32; off > 0; off >>= 1) v += __shfl_xor(v, off, 64);
  return v;
}
__device__ __forceinline__ double wredd(double v) {
  #pragma unroll
  for (int off = 32; off > 0; off >>= 1) v += __shfl_xor(v, off, 64);
  return v;
}
__device__ __forceinline__ float4 f4fma(float4 a, float4 b, float4 c) { // a*b+c
  return make_float4(fmaf(a.x,b.x,c.x), fmaf(a.y,b.y,c.y),
                     fmaf(a.z,b.z,c.z), fmaf(a.w,b.w,c.w));
}
__device__ __forceinline__ float4 f4mul(float4 a, float4 b) {
  return make_float4(a.x*b.x, a.y*b.y, a.z*b.z, a.w*b.w);
}
__device__ __forceinline__ float parse_T(const int* Tp) {
  int v = *Tp;
  if (v >= 1 && v <= 1000000000) return (float)v;
  return __int_as_float(v);
}

// ---------- K1: single serial pass (R8-proven, unchanged) ----------
__global__ __launch_bounds__(512, 4) void k_phase1(
    const float* __restrict__ t, const int* __restrict__ mi,
    const float* __restrict__ alpha, const float* __restrict__ gamma,
    const int* __restrict__ Tp,
    float4* __restrict__ cd4G, float* __restrict__ slG,
    float4* __restrict__ Cl8, float4* __restrict__ Dc8,
    float4* __restrict__ Ag, float4* __restrict__ gdec,
    float* __restrict__ compP, int N, int B)
{
  __shared__ float4 AT4[MT*MT];                       // 64 KB
  __shared__ __align__(16) unsigned char pool[8320];  // d4t+miL (serial) / cw+cwd (scan)
  __shared__ float sL[8*MAXB];                        // per-event local intensity
  __shared__ float4 asumS[MT];
  __shared__ float red[8];
  float4*        d4t = (float4*)pool;                 // [8*MAXB]
  unsigned char* miL = pool + 8*MAXB*16;              // [8*MAXB]
  float4*        cw  = (float4*)pool;                 // [512] post-serial overlay
  float4*        cwd = (float4*)(pool + 8192);        // [8]

  const int tid = threadIdx.x, lane = tid & 63, wv = tid >> 6;
  const float g0=gamma[0], g1=gamma[1], g2=gamma[2], g3=gamma[3];

  #pragma unroll
  for (int idx = tid; idx < MT*MT; idx += 512) {
    float a0=alpha[idx],         a1=alpha[MT*MT+idx];
    float a2=alpha[2*MT*MT+idx], a3=alpha[3*MT*MT+idx];
    AT4[idx] = make_float4(g0*a0, g1*a1, g2*a2, g3*a3);
  }
  if (tid < MT*KK) {
    const int m = tid >> 2, k = tid & 3;
    const float4* row = (const float4*)(alpha + (size_t)k*MT*MT + m*MT);
    float s = 0.f;
    #pragma unroll
    for (int j = 0; j < MT/4; ++j) { float4 v = row[j]; s += (v.x+v.y)+(v.z+v.w); }
    ((float*)asumS)[(m<<2)+k] = s;
  }
  __syncthreads();

  const float T = parse_T(Tp);
  const int s0w = (int)blockIdx.x * 8 * B;
  const int b  = (int)blockIdx.x*8 + wv;
  const int s0 = b*B, e0 = min(N, s0+B);
  float4 q = make_float4(0.f,0.f,0.f,0.f);
  float comp = 0.f;
  const int nch = (B + MAXB - 1) / MAXB;              // 1 for N<=200704

  for (int ch = 0; ch < nch; ++ch) {
    const int c0 = ch*MAXB;
    const int cb = min(B - c0, MAXB);
    const int tot = 8*cb;
    // ---- parallel fill: d4/mi tiles, cd4G (block-ref decay), compensator ----
    for (int jj = tid; jj < tot; jj += 512) {
      int w = jj / cb, lo = jj - w*cb;
      int i = s0w + w*B + c0 + lo;
      if (i < N) {
        float ti = t[i];
        float tp = (i > 0) ? t[i-1] : ti;
        float dt = ti - tp;
        d4t[jj] = make_float4(__expf(-g0*dt), __expf(-g1*dt),
                              __expf(-g2*dt), __expf(-g3*dt));
        int m = mi[i];
        miL[jj] = (unsigned char)m;
        int refi = s0w + w*B - 1;                     // block ref = t[block_start-1]
        float tr = (refi >= 0) ? t[refi] : t[0];
        float x = ti - tr;
        cd4G[i] = make_float4(__expf(-g0*x), __expf(-g1*x),
                              __expf(-g2*x), __expf(-g3*x));
        float y = T - ti;
        float4 as = asumS[m];
        comp = fmaf(as.x, 1.f-__expf(-g0*y), comp);
        comp = fmaf(as.y, 1.f-__expf(-g1*y), comp);
        comp = fmaf(as.z, 1.f-__expf(-g2*y), comp);
        comp = fmaf(as.w, 1.f-__expf(-g3*y), comp);
      }
    }
    __syncthreads();
    // ---- wave-per-block serial scan (LDS only; no transcendentals) ----
    const int iend = min(cb, e0 - s0 - c0);
    int j = wv*cb;
    #pragma unroll 4
    for (int ii = 0; ii < iend; ++ii, ++j) {
      float4 d = d4t[j];                              // wave-uniform broadcast
      int m = miL[j];                                 // wave-uniform
      float4 a = AT4[(m<<6) + lane];                  // 1KB/wave, conflict-free
      float s = q.x*d.x; s=fmaf(q.y,d.y,s); s=fmaf(q.z,d.z,s); s=fmaf(q.w,d.w,s);
      if (lane == m) sL[j] = s;                       // local intensity at event
      q = f4fma(q, d, a);
    }
    __syncthreads();
    // ---- copy s_loc to global (coalesced) ----
    for (int jj = tid; jj < tot; jj += 512) {
      int w = jj / cb, lo = jj - w*cb;
      int i = s0w + w*B + c0 + lo;
      if (i < N) slG[i] = sL[jj];
    }
    __syncthreads();
  }

  comp = wredf(comp);
  if (lane == 0) red[wv] = comp;

  float4 df = make_float4(1.f,1.f,1.f,1.f);
  if (lane == 0) {
    int last  = max(e0-1, 0);
    int plast = min(max(s0-1, 0), N-1);
    float dtb = t[last] - t[plast];
    df = make_float4(__expf(-g0*dtb),__expf(-g1*dtb),
                     __expf(-g2*dtb),__expf(-g3*dtb));
  }
  cw[wv*64 + lane] = q;
  if (lane == 0) cwd[wv] = df;
  __syncthreads();

  float4 c  = make_float4(0.f,0.f,0.f,0.f);
  float4 dp = make_float4(1.f,1.f,1.f,1.f);
  float4 Cl = c, Dc = dp;
  #pragma unroll
  for (int jo = 0; jo < 8; ++jo) {
    if (jo == wv) { Cl = c; Dc = dp; }
    float4 d = cwd[jo];
    float4 P = cw[jo*64 + lane];
    c  = f4fma(c, d, P);
    dp = f4mul(dp, d);
  }
  Cl8[(size_t)b*64 + lane] = Cl;
  if (lane == 0) Dc8[b] = Dc;
  if (wv == 0) {
    Ag[(size_t)blockIdx.x*64 + lane] = c;
    if (lane == 0) gdec[blockIdx.x] = dp;
    if (lane == 0) {
      float cc = 0.f;
      #pragma unroll
      for (int jr = 0; jr < 8; ++jr) cc += red[jr];
      compP[blockIdx.x] = cc;
    }
  }
}

// ---------- K2: in-WG prefetched carry hierarchy + per-event intensity ----------
// R10's structure (proven correct) + R11's batched prefetch (proven fast):
// 8 waves fold the needed supergroup aggregates (s < sup) with batch-8 loads;
// wave0 folds Top through LDS; wave1 folds gp/gd with batch-4. Then the fully
// parallel per-event intensity. Replaces the separate k_scan2 node.
__global__ __launch_bounds__(512, 4) void k_lam3(
    const int* __restrict__ mi, const float* __restrict__ mu,
    const float4* __restrict__ cd4G, const float* __restrict__ slG,
    const float4* __restrict__ Cl8, const float4* __restrict__ Dc8,
    const float4* __restrict__ Ag, const float4* __restrict__ gdec,
    float* __restrict__ npt, int N, int B)
{
  __shared__ float4 SgL[16*64];        // supergroup aggregates (16 KB)
  __shared__ float4 sdecL[16];
  __shared__ float4 TopL[64];
  __shared__ float4 gpL[64];
  __shared__ float4 gdLs;
  __shared__ float red[8];

  const int tid = threadIdx.x, lane = tid & 63, wv = tid >> 6;
  const int oct = blockIdx.x;
  const int sup = oct >> 5;
  const int BPW = 8*B;
  const int i = oct*BPW + tid;

  // ---- hoisted per-event loads (fly during the fold prologue) ----
  int   m = 0;
  float4 cd, Cl, Dc; float sl = 0.f, muv = 0.f;
  const bool valid = (tid < BPW) && (i < N);
  if (valid) {
    m  = mi[i];
    cd = cd4G[i];
    sl = slG[i];
    muv = mu[m];
    int bl = tid / B;
    int b = oct*8 + bl;
    Dc = Dc8[b];
    Cl = Cl8[(size_t)b*64 + m];
  }

  // ---- fold needed supergroup aggregates (s < sup), 8 waves, batch-8 prefetch ----
  for (int s = wv; s < sup; s += 8) {
    float4 c  = make_float4(0.f,0.f,0.f,0.f);
    float4 dp = make_float4(1.f,1.f,1.f,1.f);
    const int o0 = s*32;
    #pragma unroll
    for (int bb = 0; bb < 4; ++bb) {
      float4 av[8], gv[8];
      #pragma unroll
      for (int j = 0; j < 8; ++j) {               // 16 independent loads in flight
        const int o = o0 + bb*8 + j;
        av[j] = Ag[(size_t)o*64 + lane];
        gv[j] = gdec[o];
      }
      #pragma unroll
      for (int j = 0; j < 8; ++j) {               // register-only compose
        c  = f4fma(c, gv[j], av[j]);
        dp = f4mul(dp, gv[j]);
      }
    }
    SgL[s*64 + lane] = c;
    if (lane == 0) sdecL[s] = dp;
  }
  __syncthreads();

  if (wv == 0) {                        // Top: carry into this supergroup (<=15, LDS)
    float4 tc = make_float4(0.f,0.f,0.f,0.f);
    for (int s = 0; s < sup; ++s)
      tc = f4fma(tc, sdecL[s], SgL[s*64 + lane]);
    TopL[lane] = tc;
  } else if (wv == 1) {                 // gp/gd: carry into octet within super (<=31)
    float4 gp = make_float4(0.f,0.f,0.f,0.f);
    float4 gd = make_float4(1.f,1.f,1.f,1.f);
    int o = sup << 5;
    for (; o + 4 <= oct; o += 4) {
      float4 av[4], gv[4];
      #pragma unroll
      for (int j = 0; j < 4; ++j) {
        av[j] = Ag[(size_t)(o+j)*64 + lane];
        gv[j] = gdec[o+j];
      }
      #pragma unroll
      for (int j = 0; j < 4; ++j) {
        gp = f4fma(gp, gv[j], av[j]);
        gd = f4mul(gd, gv[j]);
      }
    }
    for (; o < oct; ++o) {
      gp = f4fma(gp, gdec[o], Ag[(size_t)o*64 + lane]);
      gd = f4mul(gd, gdec[o]);
    }
    gpL[lane] = gp;
    if (lane == 0) gdLs = gd;
  }
  __syncthreads();

  // ---- per-event intensity ----
  float v = 0.f;
  if (valid) {
    float4 coct = f4fma(gdLs, TopL[m], gpL[m]);             // carry into octet
    float4 C = f4fma(Dc, coct, Cl);                         // carry into block
    float lam = muv + sl + (C.x*cd.x + C.y*cd.y + C.z*cd.z + C.w*cd.w);
    v = __log2f(lam);
  }
  v = wredf(v);
  if (lane == 0) red[wv] = v;
  __syncthreads();
  if (tid == 0) {
    float s = 0.f;
    #pragma unroll
    for (int j = 0; j < 8; ++j) s += red[j];
    npt[oct] = s;
  }
}

// ---------- K3: deterministic final reduction ----------
__global__ __launch_bounds__(512) void k_final(
    const float* __restrict__ mu, const int* __restrict__ Tp,
    const float* __restrict__ compP, int nc,
    const float* __restrict__ npt, int nn,
    float* __restrict__ out, int N)
{
  const int tid = threadIdx.x;
  double sc = 0.0, sn = 0.0;
  for (int i = tid; i < nc; i += 512) sc += (double)compP[i];
  for (int i = tid; i < nn; i += 512) sn += (double)npt[i];
  double sm = (tid < MT) ? (double)mu[tid] : 0.0;
  sc = wredd(sc); sn = wredd(sn); sm = wredd(sm);
  __shared__ double s3[3][8];
  const int wv = tid >> 6, lane = tid & 63;
  if (lane == 0) { s3[0][wv]=sc; s3[1][wv]=sn; s3[2][wv]=sm; }
  __syncthreads();
  if (tid == 0) {
    double C=0.0, L=0.0, Mm=0.0;
    #pragma unroll
    for (int j = 0; j < 8; ++j) { C+=s3[0][j]; L+=s3[1][j]; Mm+=s3[2][j]; }
    L *= 0.6931471805599453;             // acc was log2
    double T = (double)parse_T(Tp);
    out[0] = (float)((C + T*Mm - L) / (double)N);
  }
}

extern "C" void kernel_launch(void* const* d_in, const int* in_sizes, int n_in,
                              void* d_out, int out_size, void* d_ws, size_t ws_size,
                              hipStream_t stream)
{
  const float* mu    = (const float*)d_in[0];
  const float* alpha = (const float*)d_in[1];   // (K, M, M)
  const float* gamma = (const float*)d_in[2];   // (K,)
  const float* t     = (const float*)d_in[3];   // (N,)
  const int*   mi    = (const int*)d_in[4];     // (N,) int32
  const int*   Tp    = (const int*)d_in[5];     // scalar
  const int N = in_sizes[3];
  const int B   = (N + NBK - 1) / NBK;          // 49 at N=200k
  const int NOG = NBK / 8;                      // 512 WGs / octets

  float* p = (float*)d_ws;
  float4* cd4G  = (float4*)p; p += (size_t)N*4;
  float*  slG   = p;          p += ((size_t)N + 3) & ~(size_t)3;
  float4* Cl8   = (float4*)p; p += (size_t)NBK*256;
  float4* Dc8   = (float4*)p; p += (size_t)NBK*4;
  float4* Ag    = (float4*)p; p += (size_t)NOG*256;
  float4* gdec  = (float4*)p; p += (size_t)NOG*4;
  float*  compP = p;          p += NOG;
  float*  npt   = p;          p += NOG;

  k_phase1<<<NOG, 512, 0, stream>>>(t, mi, alpha, gamma, Tp, cd4G, slG,
                                    Cl8, Dc8, Ag, gdec, compP, N, B);
  k_lam3  <<<NOG, 512, 0, stream>>>(mi, mu, cd4G, slG, Cl8, Dc8, Ag, gdec,
                                    npt, N, B);
  k_final <<<1,   512, 0, stream>>>(mu, Tp, compP, NOG, npt, NOG,
                                    (float*)d_out, N);
}

// Round 13
// 35.505 us; speedup vs baseline: 1.4390x; 1.4390x over previous
//
#include <hip/hip_runtime.h>

#define MT 64     // number of event types M
#define KK 4      // number of kernels K
#define NBK 4096  // scan blocks (512 WGs x 8 waves)
#define MAXB 52   // max events/block in LDS tiles (N <= 212992; harness N = 200000)

// ---------- helpers ----------
__device__ __forceinline__ float wredf(float v) {
  #pragma unroll
  for (int off = 32; off > 0; off >>= 1) v += __shfl_xor(v, off, 64);
  return v;
}
__device__ __forceinline__ double wredd(double v) {
  #pragma unroll
  for (int off = 32; off > 0; off >>= 1) v += __shfl_xor(v, off, 64);
  return v;
}
__device__ __forceinline__ float4 f4fma(float4 a, float4 b, float4 c) { // a*b+c
  return make_float4(fmaf(a.x,b.x,c.x), fmaf(a.y,b.y,c.y),
                     fmaf(a.z,b.z,c.z), fmaf(a.w,b.w,c.w));
}
__device__ __forceinline__ float4 f4mul(float4 a, float4 b) {
  return make_float4(a.x*b.x, a.y*b.y, a.z*b.z, a.w*b.w);
}
__device__ __forceinline__ float parse_T(const int* Tp) {
  int v = *Tp;
  if (v >= 1 && v <= 1000000000) return (float)v;
  return __int_as_float(v);
}

// ---------- K1: single pass, NO serial chain (decay-ratio form) ----------
// Per WG (octet = 8 blocks): stage AT4; one event per thread: rcp tile
// rcp_j = exp(+gamma*(t_j - r_b)) (block-span tiny -> rcp in [1,~1.05]),
// compensator; per-wave dependency-free P accumulation; per-thread pair loop
// for s_loc; intra-octet cross-wave scan -> Cl8/Dc8 + Ag/gdec.
__global__ __launch_bounds__(512, 4) void k_phase1(
    const float* __restrict__ t, const int* __restrict__ mi,
    const float* __restrict__ alpha, const float* __restrict__ gamma,
    const int* __restrict__ Tp,
    float* __restrict__ slG,
    float4* __restrict__ Cl8, float4* __restrict__ Dc8,
    float4* __restrict__ Ag, float4* __restrict__ gdec,
    float* __restrict__ compP, int N, int B)
{
  __shared__ float4 AT4[MT*MT];                       // 64 KB
  __shared__ __align__(16) unsigned char pool[8320];  // rcpt+miL / cw+cwd overlay
  __shared__ float4 asumS[MT];
  __shared__ float red[8];
  float4*        rcpt = (float4*)pool;                // [8*MAXB] decay reciprocals
  unsigned char* miL  = pool + 8*MAXB*16;             // [8*MAXB]
  float4*        cw   = (float4*)pool;                // [512] post-tile overlay
  float4*        cwd  = (float4*)(pool + 8192);       // [8]

  const int tid = threadIdx.x, lane = tid & 63, wv = tid >> 6;
  const float g0=gamma[0], g1=gamma[1], g2=gamma[2], g3=gamma[3];

  #pragma unroll
  for (int idx = tid; idx < MT*MT; idx += 512) {
    float a0=alpha[idx],         a1=alpha[MT*MT+idx];
    float a2=alpha[2*MT*MT+idx], a3=alpha[3*MT*MT+idx];
    AT4[idx] = make_float4(g0*a0, g1*a1, g2*a2, g3*a3);
  }
  if (tid < MT*KK) {
    const int m = tid >> 2, k = tid & 3;
    const float4* row = (const float4*)(alpha + (size_t)k*MT*MT + m*MT);
    float s = 0.f;
    #pragma unroll
    for (int j = 0; j < MT/4; ++j) { float4 v = row[j]; s += (v.x+v.y)+(v.z+v.w); }
    ((float*)asumS)[(m<<2)+k] = s;
  }
  __syncthreads();

  const float T = parse_T(Tp);
  const int s0w = (int)blockIdx.x * 8 * B;
  const int tot = 8 * B;                              // <= 416 -> one event/thread

  // ---- per-thread event state (persists across phases) ----
  int   mI = 0, lo = 0, bl = 0;
  float xI = 0.f;                                     // t_i - r_b
  float comp = 0.f;
  const int iG = s0w + tid;                           // i == s0w + jj (cb == B)
  const bool evOK = (tid < tot) && (iG < N);
  if (evOK) {
    bl = tid / B; lo = tid - bl*B;
    float ti = t[iG];
    int refi = s0w + bl*B - 1;
    float tr = (refi >= 0) ? t[refi] : t[0];
    xI = ti - tr;
    rcpt[tid] = make_float4(__expf(g0*xI), __expf(g1*xI),
                            __expf(g2*xI), __expf(g3*xI));
    mI = mi[iG];
    miL[tid] = (unsigned char)mI;
    float y = T - ti;
    float4 as = asumS[mI];
    comp = fmaf(as.x, 1.f-__expf(-g0*y), comp);
    comp = fmaf(as.y, 1.f-__expf(-g1*y), comp);
    comp = fmaf(as.z, 1.f-__expf(-g2*y), comp);
    comp = fmaf(as.w, 1.f-__expf(-g3*y), comp);
  }
  comp = wredf(comp);
  if (lane == 0) red[wv] = comp;
  __syncthreads();                                    // tiles ready

  // ---- per-wave dependency-free P accumulation (wave wv owns block wv) ----
  const int b  = (int)blockIdx.x*8 + wv;
  const int s0 = b*B, e0 = min(N, s0+B);
  const int iend = max(e0 - s0, 0);
  float4 S = make_float4(0.f,0.f,0.f,0.f);
  {
    const int base = wv*B;
    #pragma unroll 4
    for (int ii = 0; ii < iend; ++ii) {
      float4 r = rcpt[base + ii];                     // wave-uniform
      int m = miL[base + ii];                         // wave-uniform
      float4 a = AT4[(m<<6) + lane];                  // 1KB/wave, conflict-free
      S = f4fma(a, r, S);                             // no loop-carried dependence
    }
  }
  float4 q;                                           // P = cd_last * S
  {
    float xl = 0.f;
    if (iend > 0) {
      int refi = s0 - 1;
      float tr = (refi >= 0) ? t[refi] : t[0];
      xl = t[e0-1] - tr;
    }
    float4 cdl = make_float4(__expf(-g0*xl), __expf(-g1*xl),
                             __expf(-g2*xl), __expf(-g3*xl));
    q = f4mul(S, cdl);
  }

  // ---- per-thread pair loop: s_loc[i] = cd_i . sum_{j<i} rcp_j (.) AT4[m_j][m_i]
  if (evOK) {
    const int jb = bl*B;
    float4 S4 = make_float4(0.f,0.f,0.f,0.f);
    for (int jj = 0; jj < lo; ++jj) {
      int mj = miL[jb + jj];
      float4 r = rcpt[jb + jj];
      float4 a = AT4[(mj<<6) + mI];
      S4 = f4fma(a, r, S4);
    }
    float4 cdi = make_float4(__expf(-g0*xI), __expf(-g1*xI),
                             __expf(-g2*xI), __expf(-g3*xI));
    slG[iG] = S4.x*cdi.x + S4.y*cdi.y + S4.z*cdi.z + S4.w*cdi.w;
  }

  // ---- block decay factor ----
  float4 df = make_float4(1.f,1.f,1.f,1.f);
  if (lane == 0) {
    int last  = max(e0-1, 0);
    int plast = min(max(s0-1, 0), N-1);
    float dtb = t[last] - t[plast];
    df = make_float4(__expf(-g0*dtb),__expf(-g1*dtb),
                     __expf(-g2*dtb),__expf(-g3*dtb));
  }
  __syncthreads();                                    // all tile reads done
  cw[wv*64 + lane] = q;
  if (lane == 0) cwd[wv] = df;
  __syncthreads();

  // ---- intra-octet cross-wave scan ----
  float4 c  = make_float4(0.f,0.f,0.f,0.f);
  float4 dp = make_float4(1.f,1.f,1.f,1.f);
  float4 Cl = c, Dc = dp;
  #pragma unroll
  for (int jo = 0; jo < 8; ++jo) {
    if (jo == wv) { Cl = c; Dc = dp; }
    float4 d = cwd[jo];
    float4 P = cw[jo*64 + lane];
    c  = f4fma(c, d, P);
    dp = f4mul(dp, d);
  }
  Cl8[(size_t)b*64 + lane] = Cl;
  if (lane == 0) Dc8[b] = Dc;
  if (wv == 0) {
    Ag[(size_t)blockIdx.x*64 + lane] = c;
    if (lane == 0) gdec[blockIdx.x] = dp;
    if (lane == 0) {
      float cc = 0.f;
      #pragma unroll
      for (int jr = 0; jr < 8; ++jr) cc += red[jr];
      compP[blockIdx.x] = cc;
    }
  }
}

// ---------- K2: supergroup aggregates — batched prefetch (R11-proven) ----------
__global__ __launch_bounds__(64) void k_scan2(
    const float4* __restrict__ Ag, const float4* __restrict__ gdec,
    float4* __restrict__ SgG, float4* __restrict__ sdecG)
{
  const int lane = threadIdx.x;
  const int s = blockIdx.x;
  float4 c  = make_float4(0.f,0.f,0.f,0.f);
  float4 dp = make_float4(1.f,1.f,1.f,1.f);
  const int o0 = s*32;
  #pragma unroll
  for (int bb = 0; bb < 4; ++bb) {
    float4 av[8], gv[8];
    #pragma unroll
    for (int j = 0; j < 8; ++j) {               // 16 independent loads in flight
      const int o = o0 + bb*8 + j;
      av[j] = Ag[(size_t)o*64 + lane];
      gv[j] = gdec[o];
    }
    #pragma unroll
    for (int j = 0; j < 8; ++j) {               // register-only compose
      c  = f4fma(c, gv[j], av[j]);
      dp = f4mul(dp, gv[j]);
    }
  }
  SgG[(size_t)s*64 + lane] = c;
  if (lane == 0) sdecG[s] = dp;
}

// ---------- K3: per-event intensity; cd recomputed from t (no cd4G) ----------
__global__ __launch_bounds__(512, 4) void k_lam(
    const float* __restrict__ t, const int* __restrict__ mi,
    const float* __restrict__ gamma, const float* __restrict__ mu,
    const float* __restrict__ slG,
    const float4* __restrict__ Cl8, const float4* __restrict__ Dc8,
    const float4* __restrict__ Ag, const float4* __restrict__ gdec,
    const float4* __restrict__ SgG, const float4* __restrict__ sdecG,
    float* __restrict__ npt, int N, int B)
{
  __shared__ float4 TopL[64];
  __shared__ float4 gpL[64];
  __shared__ float4 gdLs;
  __shared__ float red[8];
  const int tid = threadIdx.x, lane = tid & 63, wv = tid >> 6;
  const int oct = blockIdx.x;
  const int sup = oct >> 5;
  const int BPW = 8*B;
  const int i = oct*BPW + tid;

  // ---- hoisted per-event loads (fly during the fold prologue) ----
  int   m = 0;
  float4 cd, Cl, Dc; float sl = 0.f, muv = 0.f;
  const bool valid = (tid < BPW) && (i < N);
  if (valid) {
    m  = mi[i];
    sl = slG[i];
    muv = mu[m];
    int bl = tid / B;
    int b = oct*8 + bl;
    float ti = t[i];
    int refi = b*B - 1;
    float tr = (refi >= 0) ? t[refi] : t[0];
    float x = ti - tr;
    const float g0=gamma[0], g1=gamma[1], g2=gamma[2], g3=gamma[3];
    cd = make_float4(__expf(-g0*x), __expf(-g1*x), __expf(-g2*x), __expf(-g3*x));
    Dc = Dc8[b];
    Cl = Cl8[(size_t)b*64 + m];
  }

  if (wv == 0) {                        // Top: carry into this supergroup (<=15 steps)
    float4 tc = make_float4(0.f,0.f,0.f,0.f);
    int s = 0;
    for (; s + 4 <= sup; s += 4) {
      float4 av[4], gv[4];
      #pragma unroll
      for (int j = 0; j < 4; ++j) {
        av[j] = SgG[(size_t)(s+j)*64 + lane];
        gv[j] = sdecG[s+j];
      }
      #pragma unroll
      for (int j = 0; j < 4; ++j) tc = f4fma(tc, gv[j], av[j]);
    }
    for (; s < sup; ++s) tc = f4fma(tc, sdecG[s], SgG[(size_t)s*64 + lane]);
    TopL[lane] = tc;
  } else if (wv == 1) {                 // gp/gd: carry into octet within super (<=31)
    float4 gp = make_float4(0.f,0.f,0.f,0.f);
    float4 gd = make_float4(1.f,1.f,1.f,1.f);
    int o = sup << 5;
    for (; o + 4 <= oct; o += 4) {
      float4 av[4], gv[4];
      #pragma unroll
      for (int j = 0; j < 4; ++j) {
        av[j] = Ag[(size_t)(o+j)*64 + lane];
        gv[j] = gdec[o+j];
      }
      #pragma unroll
      for (int j = 0; j < 4; ++j) {
        gp = f4fma(gp, gv[j], av[j]);
        gd = f4mul(gd, gv[j]);
      }
    }
    for (; o < oct; ++o) {
      gp = f4fma(gp, gdec[o], Ag[(size_t)o*64 + lane]);
      gd = f4mul(gd, gdec[o]);
    }
    gpL[lane] = gp;
    if (lane == 0) gdLs = gd;
  }
  __syncthreads();

  // ---- per-event intensity ----
  float v = 0.f;
  if (valid) {
    float4 coct = f4fma(gdLs, TopL[m], gpL[m]);             // carry into octet
    float4 C = f4fma(Dc, coct, Cl);                         // carry into block
    float lam = muv + sl + (C.x*cd.x + C.y*cd.y + C.z*cd.z + C.w*cd.w);
    v = __log2f(lam);
  }
  v = wredf(v);
  if (lane == 0) red[wv] = v;
  __syncthreads();
  if (tid == 0) {
    float s = 0.f;
    #pragma unroll
    for (int j = 0; j < 8; ++j) s += red[j];
    npt[oct] = s;
  }
}

// ---------- K4: deterministic final reduction ----------
__global__ __launch_bounds__(512) void k_final(
    const float* __restrict__ mu, const int* __restrict__ Tp,
    const float* __restrict__ compP, int nc,
    const float* __restrict__ npt, int nn,
    float* __restrict__ out, int N)
{
  const int tid = threadIdx.x;
  double sc = 0.0, sn = 0.0;
  for (int i = tid; i < nc; i += 512) sc += (double)compP[i];
  for (int i = tid; i < nn; i += 512) sn += (double)npt[i];
  double sm = (tid < MT) ? (double)mu[tid] : 0.0;
  sc = wredd(sc); sn = wredd(sn); sm = wredd(sm);
  __shared__ double s3[3][8];
  const int wv = tid >> 6, lane = tid & 63;
  if (lane == 0) { s3[0][wv]=sc; s3[1][wv]=sn; s3[2][wv]=sm; }
  __syncthreads();
  if (tid == 0) {
    double C=0.0, L=0.0, Mm=0.0;
    #pragma unroll
    for (int j = 0; j < 8; ++j) { C+=s3[0][j]; L+=s3[1][j]; Mm+=s3[2][j]; }
    L *= 0.6931471805599453;             // acc was log2
    double T = (double)parse_T(Tp);
    out[0] = (float)((C + T*Mm - L) / (double)N);
  }
}

extern "C" void kernel_launch(void* const* d_in, const int* in_sizes, int n_in,
                              void* d_out, int out_size, void* d_ws, size_t ws_size,
                              hipStream_t stream)
{
  const float* mu    = (const float*)d_in[0];
  const float* alpha = (const float*)d_in[1];   // (K, M, M)
  const float* gamma = (const float*)d_in[2];   // (K,)
  const float* t     = (const float*)d_in[3];   // (N,)
  const int*   mi    = (const int*)d_in[4];     // (N,) int32
  const int*   Tp    = (const int*)d_in[5];     // scalar
  const int N = in_sizes[3];
  const int B   = (N + NBK - 1) / NBK;          // 49 at N=200k (<= MAXB)
  const int NOG = NBK / 8;                      // 512 WGs / octets

  float* p = (float*)d_ws;
  float*  slG   = p;          p += ((size_t)N + 3) & ~(size_t)3;
  float4* Cl8   = (float4*)p; p += (size_t)NBK*256;
  float4* Dc8   = (float4*)p; p += (size_t)NBK*4;
  float4* Ag    = (float4*)p; p += (size_t)NOG*256;
  float4* gdec  = (float4*)p; p += (size_t)NOG*4;
  float4* SgG   = (float4*)p; p += (size_t)16*256;
  float4* sdecG = (float4*)p; p += (size_t)16*4;
  float*  compP = p;          p += NOG;
  float*  npt   = p;          p += NOG;

  k_phase1<<<NOG, 512, 0, stream>>>(t, mi, alpha, gamma, Tp, slG,
                                    Cl8, Dc8, Ag, gdec, compP, N, B);
  k_scan2 <<<16,  64,  0, stream>>>(Ag, gdec, SgG, sdecG);
  k_lam   <<<NOG, 512, 0, stream>>>(t, mi, gamma, mu, slG, Cl8, Dc8, Ag, gdec,
                                    SgG, sdecG, npt, N, B);
  k_final <<<1,   512, 0, stream>>>(mu, Tp, compP, NOG, npt, NOG,
                                    (float*)d_out, N);
}

// Round 14
// 32.614 us; speedup vs baseline: 1.5666x; 1.0887x over previous
//
#include <hip/hip_runtime.h>

#define MT 64     // number of event types M
#define KK 4      // number of kernels K
#define NBK 4096  // scan blocks (512 WGs x 8 waves)
#define MAXB 49   // events/block per LDS chunk (N <= 200704 in one chunk; larger N loops)

// ---------- helpers ----------
__device__ __forceinline__ float wredf(float v) {
  #pragma unroll
  for (int off = 32; off > 0; off >>= 1) v += __shfl_xor(v, off, 64);
  return v;
}
__device__ __forceinline__ double wredd(double v) {
  #pragma unroll
  for (int off = 32; off > 0; off >>= 1) v += __shfl_xor(v, off, 64);
  return v;
}
__device__ __forceinline__ float4 f4fma(float4 a, float4 b, float4 c) { // a*b+c
  return make_float4(fmaf(a.x,b.x,c.x), fmaf(a.y,b.y,c.y),
                     fmaf(a.z,b.z,c.z), fmaf(a.w,b.w,c.w));
}
__device__ __forceinline__ float4 f4mul(float4 a, float4 b) {
  return make_float4(a.x*b.x, a.y*b.y, a.z*b.z, a.w*b.w);
}
__device__ __forceinline__ float parse_T(const int* Tp) {
  int v = *Tp;
  if (v >= 1 && v <= 1000000000) return (float)v;
  return __int_as_float(v);
}

// ---------- K1: single serial pass (R11-proven, minus cd4G store) ----------
__global__ __launch_bounds__(512, 4) void k_phase1(
    const float* __restrict__ t, const int* __restrict__ mi,
    const float* __restrict__ alpha, const float* __restrict__ gamma,
    const int* __restrict__ Tp,
    float* __restrict__ slG,
    float4* __restrict__ Cl8, float4* __restrict__ Dc8,
    float4* __restrict__ Ag, float4* __restrict__ gdec,
    float* __restrict__ compP, int N, int B)
{
  __shared__ float4 AT4[MT*MT];                       // 64 KB
  __shared__ __align__(16) unsigned char pool[8320];  // d4t+miL (serial) / cw+cwd (scan)
  __shared__ float sL[8*MAXB];                        // per-event local intensity
  __shared__ float4 asumS[MT];
  __shared__ float red[8];
  float4*        d4t = (float4*)pool;                 // [8*MAXB]
  unsigned char* miL = pool + 8*MAXB*16;              // [8*MAXB]
  float4*        cw  = (float4*)pool;                 // [512] post-serial overlay
  float4*        cwd = (float4*)(pool + 8192);        // [8]

  const int tid = threadIdx.x, lane = tid & 63, wv = tid >> 6;
  const float g0=gamma[0], g1=gamma[1], g2=gamma[2], g3=gamma[3];

  #pragma unroll
  for (int idx = tid; idx < MT*MT; idx += 512) {
    float a0=alpha[idx],         a1=alpha[MT*MT+idx];
    float a2=alpha[2*MT*MT+idx], a3=alpha[3*MT*MT+idx];
    AT4[idx] = make_float4(g0*a0, g1*a1, g2*a2, g3*a3);
  }
  if (tid < MT*KK) {
    const int m = tid >> 2, k = tid & 3;
    const float4* row = (const float4*)(alpha + (size_t)k*MT*MT + m*MT);
    float s = 0.f;
    #pragma unroll
    for (int j = 0; j < MT/4; ++j) { float4 v = row[j]; s += (v.x+v.y)+(v.z+v.w); }
    ((float*)asumS)[(m<<2)+k] = s;
  }
  __syncthreads();

  const float T = parse_T(Tp);
  const int s0w = (int)blockIdx.x * 8 * B;
  const int b  = (int)blockIdx.x*8 + wv;
  const int s0 = b*B, e0 = min(N, s0+B);
  float4 q = make_float4(0.f,0.f,0.f,0.f);
  float comp = 0.f;
  const int nch = (B + MAXB - 1) / MAXB;              // 1 for N<=200704

  for (int ch = 0; ch < nch; ++ch) {
    const int c0 = ch*MAXB;
    const int cb = min(B - c0, MAXB);
    const int tot = 8*cb;
    // ---- parallel fill: d4/mi tiles + compensator ----
    for (int jj = tid; jj < tot; jj += 512) {
      int w = jj / cb, lo = jj - w*cb;
      int i = s0w + w*B + c0 + lo;
      if (i < N) {
        float ti = t[i];
        float tp = (i > 0) ? t[i-1] : ti;
        float dt = ti - tp;
        d4t[jj] = make_float4(__expf(-g0*dt), __expf(-g1*dt),
                              __expf(-g2*dt), __expf(-g3*dt));
        int m = mi[i];
        miL[jj] = (unsigned char)m;
        float y = T - ti;
        float4 as = asumS[m];
        comp = fmaf(as.x, 1.f-__expf(-g0*y), comp);
        comp = fmaf(as.y, 1.f-__expf(-g1*y), comp);
        comp = fmaf(as.z, 1.f-__expf(-g2*y), comp);
        comp = fmaf(as.w, 1.f-__expf(-g3*y), comp);
      }
    }
    __syncthreads();
    // ---- wave-per-block serial scan (LDS only; no transcendentals) ----
    const int iend = min(cb, e0 - s0 - c0);
    int j = wv*cb;
    #pragma unroll 4
    for (int ii = 0; ii < iend; ++ii, ++j) {
      float4 d = d4t[j];                              // wave-uniform broadcast
      int m = miL[j];                                 // wave-uniform
      float4 a = AT4[(m<<6) + lane];                  // 1KB/wave, conflict-free
      float s = q.x*d.x; s=fmaf(q.y,d.y,s); s=fmaf(q.z,d.z,s); s=fmaf(q.w,d.w,s);
      if (lane == m) sL[j] = s;                       // local intensity at event
      q = f4fma(q, d, a);
    }
    __syncthreads();
    // ---- copy s_loc to global (coalesced) ----
    for (int jj = tid; jj < tot; jj += 512) {
      int w = jj / cb, lo = jj - w*cb;
      int i = s0w + w*B + c0 + lo;
      if (i < N) slG[i] = sL[jj];
    }
    __syncthreads();
  }

  comp = wredf(comp);
  if (lane == 0) red[wv] = comp;

  float4 df = make_float4(1.f,1.f,1.f,1.f);
  if (lane == 0) {
    int last  = max(e0-1, 0);
    int plast = min(max(s0-1, 0), N-1);
    float dtb = t[last] - t[plast];
    df = make_float4(__expf(-g0*dtb),__expf(-g1*dtb),
                     __expf(-g2*dtb),__expf(-g3*dtb));
  }
  cw[wv*64 + lane] = q;
  if (lane == 0) cwd[wv] = df;
  __syncthreads();

  float4 c  = make_float4(0.f,0.f,0.f,0.f);
  float4 dp = make_float4(1.f,1.f,1.f,1.f);
  float4 Cl = c, Dc = dp;
  #pragma unroll
  for (int jo = 0; jo < 8; ++jo) {
    if (jo == wv) { Cl = c; Dc = dp; }
    float4 d = cwd[jo];
    float4 P = cw[jo*64 + lane];
    c  = f4fma(c, d, P);
    dp = f4mul(dp, d);
  }
  Cl8[(size_t)b*64 + lane] = Cl;
  if (lane == 0) Dc8[b] = Dc;
  if (wv == 0) {
    Ag[(size_t)blockIdx.x*64 + lane] = c;
    if (lane == 0) gdec[blockIdx.x] = dp;
    if (lane == 0) {
      float cc = 0.f;
      #pragma unroll
      for (int jr = 0; jr < 8; ++jr) cc += red[jr];
      compP[blockIdx.x] = cc;
    }
  }
}

// ---------- K2: supergroup aggregates — batched prefetch (R11-proven) ----------
__global__ __launch_bounds__(64) void k_scan2(
    const float4* __restrict__ Ag, const float4* __restrict__ gdec,
    float4* __restrict__ SgG, float4* __restrict__ sdecG)
{
  const int lane = threadIdx.x;
  const int s = blockIdx.x;
  float4 c  = make_float4(0.f,0.f,0.f,0.f);
  float4 dp = make_float4(1.f,1.f,1.f,1.f);
  const int o0 = s*32;
  #pragma unroll
  for (int bb = 0; bb < 4; ++bb) {
    float4 av[8], gv[8];
    #pragma unroll
    for (int j = 0; j < 8; ++j) {               // 16 independent loads in flight
      const int o = o0 + bb*8 + j;
      av[j] = Ag[(size_t)o*64 + lane];
      gv[j] = gdec[o];
    }
    #pragma unroll
    for (int j = 0; j < 8; ++j) {               // register-only compose
      c  = f4fma(c, gv[j], av[j]);
      dp = f4mul(dp, gv[j]);
    }
  }
  SgG[(size_t)s*64 + lane] = c;
  if (lane == 0) sdecG[s] = dp;
}

// ---------- K3: per-event intensity; cd recomputed from t; C_L carry table in LDS ----------
__global__ __launch_bounds__(512, 4) void k_lam(
    const float* __restrict__ t, const int* __restrict__ mi,
    const float* __restrict__ gamma, const float* __restrict__ mu,
    const float* __restrict__ slG,
    const float4* __restrict__ Cl8, const float4* __restrict__ Dc8,
    const float4* __restrict__ Ag, const float4* __restrict__ gdec,
    const float4* __restrict__ SgG, const float4* __restrict__ sdecG,
    float* __restrict__ npt, int N, int B)
{
  __shared__ float4 TopL[64];
  __shared__ float4 gpL[64];
  __shared__ float4 gdLs;
  __shared__ float4 C_L[8*64];         // per-(block,m) composed carry, 8 KB
  __shared__ float red[8];
  const int tid = threadIdx.x, lane = tid & 63, wv = tid >> 6;
  const int oct = blockIdx.x;
  const int sup = oct >> 5;
  const int BPW = 8*B;
  const int i = oct*BPW + tid;
  const float g0=gamma[0], g1=gamma[1], g2=gamma[2], g3=gamma[3];

  // ---- hoisted per-event loads (fly during the fold prologue) ----
  int   m = 0;
  float4 cd; float sl = 0.f, muv = 0.f;
  const bool valid = (tid < BPW) && (i < N);
  if (valid) {
    m  = mi[i];
    sl = slG[i];
    muv = mu[m];
    int bl = tid / B;
    float ti = t[i];
    int refi = (oct*8 + bl)*B - 1;
    float tr = (refi >= 0) ? t[refi] : t[0];
    float x = ti - tr;
    cd = make_float4(__expf(-g0*x), __expf(-g1*x), __expf(-g2*x), __expf(-g3*x));
  }

  if (wv == 0) {                        // Top: carry into this supergroup (<=15 steps)
    float4 tc = make_float4(0.f,0.f,0.f,0.f);
    int s = 0;
    for (; s + 4 <= sup; s += 4) {
      float4 av[4], gv[4];
      #pragma unroll
      for (int j = 0; j < 4; ++j) {
        av[j] = SgG[(size_t)(s+j)*64 + lane];
        gv[j] = sdecG[s+j];
      }
      #pragma unroll
      for (int j = 0; j < 4; ++j) tc = f4fma(tc, gv[j], av[j]);
    }
    for (; s < sup; ++s) tc = f4fma(tc, sdecG[s], SgG[(size_t)s*64 + lane]);
    TopL[lane] = tc;
  } else if (wv == 1) {                 // gp/gd: carry into octet within super (<=31)
    float4 gp = make_float4(0.f,0.f,0.f,0.f);
    float4 gd = make_float4(1.f,1.f,1.f,1.f);
    int o = sup << 5;
    for (; o + 4 <= oct; o += 4) {
      float4 av[4], gv[4];
      #pragma unroll
      for (int j = 0; j < 4; ++j) {
        av[j] = Ag[(size_t)(o+j)*64 + lane];
        gv[j] = gdec[o+j];
      }
      #pragma unroll
      for (int j = 0; j < 4; ++j) {
        gp = f4fma(gp, gv[j], av[j]);
        gd = f4mul(gd, gv[j]);
      }
    }
    for (; o < oct; ++o) {
      gp = f4fma(gp, gdec[o], Ag[(size_t)o*64 + lane]);
      gd = f4mul(gd, gdec[o]);
    }
    gpL[lane] = gp;
    if (lane == 0) gdLs = gd;
  }
  __syncthreads();

  // ---- build per-(block,m) carry table: 512 threads = 8 blocks x 64 m, coalesced ----
  {
    const int bl2 = wv;                               // block index within octet
    const int m2  = lane;                             // type index
    const int b2  = oct*8 + bl2;
    float4 coct = f4fma(gdLs, TopL[m2], gpL[m2]);     // carry into octet, type m2
    C_L[(bl2<<6) + m2] = f4fma(Dc8[b2], coct, Cl8[(size_t)b2*64 + m2]);
  }
  __syncthreads();

  // ---- per-event intensity ----
  float v = 0.f;
  if (valid) {
    int bl = tid / B;
    float4 C = C_L[(bl<<6) + m];
    float lam = muv + sl + (C.x*cd.x + C.y*cd.y + C.z*cd.z + C.w*cd.w);
    v = __log2f(lam);
  }
  v = wredf(v);
  if (lane == 0) red[wv] = v;
  __syncthreads();
  if (tid == 0) {
    float s = 0.f;
    #pragma unroll
    for (int j = 0; j < 8; ++j) s += red[j];
    npt[oct] = s;
  }
}

// ---------- K4: deterministic final reduction ----------
__global__ __launch_bounds__(512) void k_final(
    const float* __restrict__ mu, const int* __restrict__ Tp,
    const float* __restrict__ compP, int nc,
    const float* __restrict__ npt, int nn,
    float* __restrict__ out, int N)
{
  const int tid = threadIdx.x;
  double sc = 0.0, sn = 0.0;
  for (int i = tid; i < nc; i += 512) sc += (double)compP[i];
  for (int i = tid; i < nn; i += 512) sn += (double)npt[i];
  double sm = (tid < MT) ? (double)mu[tid] : 0.0;
  sc = wredd(sc); sn = wredd(sn); sm = wredd(sm);
  __shared__ double s3[3][8];
  const int wv = tid >> 6, lane = tid & 63;
  if (lane == 0) { s3[0][wv]=sc; s3[1][wv]=sn; s3[2][wv]=sm; }
  __syncthreads();
  if (tid == 0) {
    double C=0.0, L=0.0, Mm=0.0;
    #pragma unroll
    for (int j = 0; j < 8; ++j) { C+=s3[0][j]; L+=s3[1][j]; Mm+=s3[2][j]; }
    L *= 0.6931471805599453;             // acc was log2
    double T = (double)parse_T(Tp);
    out[0] = (float)((C + T*Mm - L) / (double)N);
  }
}

extern "C" void kernel_launch(void* const* d_in, const int* in_sizes, int n_in,
                              void* d_out, int out_size, void* d_ws, size_t ws_size,
                              hipStream_t stream)
{
  const float* mu    = (const float*)d_in[0];
  const float* alpha = (const float*)d_in[1];   // (K, M, M)
  const float* gamma = (const float*)d_in[2];   // (K,)
  const float* t     = (const float*)d_in[3];   // (N,)
  const int*   mi    = (const int*)d_in[4];     // (N,) int32
  const int*   Tp    = (const int*)d_in[5];     // scalar
  const int N = in_sizes[3];
  const int B   = (N + NBK - 1) / NBK;          // 49 at N=200k
  const int NOG = NBK / 8;                      // 512 WGs / octets

  float* p = (float*)d_ws;
  float*  slG   = p;          p += ((size_t)N + 3) & ~(size_t)3;
  float4* Cl8   = (float4*)p; p += (size_t)NBK*256;
  float4* Dc8   = (float4*)p; p += (size_t)NBK*4;
  float4* Ag    = (float4*)p; p += (size_t)NOG*256;
  float4* gdec  = (float4*)p; p += (size_t)NOG*4;
  float4* SgG   = (float4*)p; p += (size_t)16*256;
  float4* sdecG = (float4*)p; p += (size_t)16*4;
  float*  compP = p;          p += NOG;
  float*  npt   = p;          p += NOG;

  k_phase1<<<NOG, 512, 0, stream>>>(t, mi, alpha, gamma, Tp, slG,
                                    Cl8, Dc8, Ag, gdec, compP, N, B);
  k_scan2 <<<16,  64,  0, stream>>>(Ag, gdec, SgG, sdecG);
  k_lam   <<<NOG, 512, 0, stream>>>(t, mi, gamma, mu, slG, Cl8, Dc8, Ag, gdec,
                                    SgG, sdecG, npt, N, B);
  k_final <<<1,   512, 0, stream>>>(mu, Tp, compP, NOG, npt, NOG,
                                    (float*)d_out, N);
}